// Round 7
// baseline (93.831 us; speedup 1.0000x reference)
//
#include <hip/hip_runtime.h>

#define N_ATOMS 50000
#define KMAX 32
#define EMB_ATOM 256
#define EP_IN 64
#define EP_OUT 64
#define EMB_RBF 16
#define NEDGES (N_ATOMS * KMAX)

typedef _Float16 half_t;
typedef __attribute__((ext_vector_type(2))) _Float16 half2_t;
typedef __attribute__((ext_vector_type(4))) _Float16 half4_t;
typedef __attribute__((ext_vector_type(8))) _Float16 half8_t;
typedef __attribute__((ext_vector_type(4))) float f32x4;

#define NATILE 32
#define FUSED_NB ((N_ATOMS + NATILE - 1) / NATILE)   // 1563 (last block clamped)

#define GLOAD_LDS16(g, l)                                                     \
    __builtin_amdgcn_global_load_lds(                                         \
        (const __attribute__((address_space(1))) void*)(g),                   \
        (__attribute__((address_space(3))) void*)(l), 16, 0, 0)

// grid partition of prep_all
#define XB_NB 782                       // ceil(50000/64)
#define SC_NB (NEDGES / 256)            // 6250
#define WB_NB 256
#define WU_NB 64
#define PREP_NB (XB_NB + SC_NB + WB_NB + WU_NB + 1)

// ---------------------------------------------------------------------------
// prep_all: one launch for everything before `fused`. (unchanged from r6)
// ---------------------------------------------------------------------------
__global__ __launch_bounds__(256) void prep_all(const float* __restrict__ h,
                                                const float* __restrict__ Wd,
                                                const int*   __restrict__ ei,
                                                const int*   __restrict__ tni,
                                                const float* __restrict__ Wb,
                                                const float* __restrict__ Wu,
                                                half_t* __restrict__ xbh,
                                                int*    __restrict__ sidx,
                                                half_t* __restrict__ Wb2,
                                                half_t* __restrict__ Wu2,
                                                half_t* __restrict__ zrow) {
    __shared__ float As[16 * 68];
    __shared__ float Bs[16 * 64];
    const int bid = blockIdx.x;
    const int t = threadIdx.x;

    if (bid < XB_NB) {
        const int r0 = bid * 64;
        const int tr = t >> 4, tc = t & 15;
        float acc[4][4] = {};
        for (int k0 = 0; k0 < 256; k0 += 16) {
            {
                int m = t >> 2, kk0 = (t & 3) << 2;
                int row = r0 + m;
                float4 v = make_float4(0.f, 0.f, 0.f, 0.f);
                if (row < N_ATOMS)
                    v = *reinterpret_cast<const float4*>(&h[(size_t)row * 256 + k0 + kk0]);
                As[(kk0 + 0) * 68 + m] = v.x;
                As[(kk0 + 1) * 68 + m] = v.y;
                As[(kk0 + 2) * 68 + m] = v.z;
                As[(kk0 + 3) * 68 + m] = v.w;
            }
            {
                int kk = t >> 4, n0 = (t & 15) << 2;
                *reinterpret_cast<float4*>(&Bs[kk * 64 + n0]) =
                    *reinterpret_cast<const float4*>(&Wd[(k0 + kk) * 64 + n0]);
            }
            __syncthreads();
            #pragma unroll
            for (int kk = 0; kk < 16; ++kk) {
                float4 av = *reinterpret_cast<const float4*>(&As[kk * 68 + tr * 4]);
                float4 bv = *reinterpret_cast<const float4*>(&Bs[kk * 64 + tc * 4]);
                float aa[4] = {av.x, av.y, av.z, av.w};
                float bb[4] = {bv.x, bv.y, bv.z, bv.w};
                #pragma unroll
                for (int i = 0; i < 4; ++i)
                    #pragma unroll
                    for (int j = 0; j < 4; ++j) acc[i][j] += aa[i] * bb[j];
            }
            __syncthreads();
        }
        #pragma unroll
        for (int i = 0; i < 4; ++i) {
            int row = r0 + tr * 4 + i;
            if (row < N_ATOMS) {
                half4_t hv;
                #pragma unroll
                for (int j = 0; j < 4; ++j) hv[j] = (half_t)acc[i][j];
                *reinterpret_cast<half4_t*>(&xbh[(size_t)row * 64 + tc * 4]) = hv;
            }
        }
    } else if (bid < XB_NB + SC_NB) {
        int i = (bid - XB_NB) * 256 + t;
        int s = ei[i];
        int d = ei[NEDGES + i];
        int k = tni[i];
        sidx[d * KMAX + k] = s;
    } else if (bid < XB_NB + SC_NB + WB_NB) {
        // Wb2[i]: e=i&7 | l=(i>>3)&63 | j=(i>>9)&15 | kh=(i>>13)&1 | ot=i>>14
        int i = (bid - XB_NB - SC_NB) * 256 + t;
        int e = i & 7, lv = (i >> 3) & 63;
        int c = lv & 15, g = lv >> 4;
        int kh = (i >> 13) & 1, ot = i >> 14;
        int o = ot * 16 + c;
        int idx = kh * 512 + ((i >> 9) & 15) * 32 + g * 8 + e;
        int r = ((idx >> 6) & 3) * 4 + (idx & 3);
        int p = (idx >> 8) * 16 + ((idx >> 2) & 15);
        Wb2[i] = (half_t)Wb[(size_t)(r * 64 + p) * 64 + o];
    } else if (bid < XB_NB + SC_NB + WB_NB + WU_NB) {
        // Wu2[i]: e=i&7 | l=(i>>3)&63 | kk=(i>>9)&1 | nt=(i>>10)&1 | w=i>>11
        int i = (bid - XB_NB - SC_NB - WB_NB) * 256 + t;
        int e = i & 7, lv = (i >> 3) & 63;
        int c = lv & 15, g = lv >> 4;
        int kk = (i >> 9) & 1, nt = (i >> 10) & 1, w = i >> 11;
        int oc = w * 32 + nt * 16 + c;
        int o = kk * 32 + g * 8 + e;
        Wu2[i] = (half_t)Wu[(size_t)o * 256 + oc];
    } else {
        if (t < 128) zrow[t] = (half_t)0.f;
    }
}

// ---------------------------------------------------------------------------
// consume one staged kc-batch (16 gathered rows) at LDS byte pointer stb
// ---------------------------------------------------------------------------
__device__ __forceinline__ void consume_batch(const char* stb, int c, int g,
                                              half4_t radf, half4_t ident,
                                              f32x4 (&acc)[4]) {
    const f32x4 fzero = {0.f, 0.f, 0.f, 0.f};
    #pragma unroll
    for (int pc = 0; pc < 4; ++pc) {
        int slot = (pc * 2 + (g >> 1)) ^ (c & 7);
        half4_t gf = *reinterpret_cast<const half4_t*>(
            stb + c * 128 + slot * 16 + (g & 1) * 8);
        // layout-convert A-frag -> B-frag via identity mfma (exact)
        f32x4 tD = __builtin_amdgcn_mfma_f32_16x16x16f16(gf, ident, fzero, 0, 0, 0);
        half4_t b2;
        #pragma unroll
        for (int j = 0; j < 4; ++j) b2[j] = (half_t)tD[j];
        acc[pc] = __builtin_amdgcn_mfma_f32_16x16x16f16(radf, b2, acc[pc], 0, 0, 0);
    }
}

// issue one kc-batch (2 x global_load_lds, 1 KB each) into atom region a_
// sidx values from wave-resident sv regs (svv covers 2 atoms; a_&1 selects)
#define ISSUE2(a_, kc_, svv) do {                                             \
    _Pragma("unroll")                                                         \
    for (int h_ = 0; h_ < 2; ++h_) {                                          \
        int s_ = __shfl(svv, ((a_) & 1) * 32 + (kc_) * 16 + h_ * 8 + (l >> 3), 64); \
        const half_t* src_ = ((unsigned)s_ < (unsigned)N_ATOMS)               \
            ? (xbh + (size_t)s_ * 64) : zrow;                                 \
        src_ += (((l & 7) ^ (l >> 3)) << 3);  /* swizzled 16B chunk */        \
        GLOAD_LDS16(src_, (half_t*)(Rb + (a_) * 2048) + h_ * 512);            \
    }                                                                         \
} while (0)

#define WRITE_ATOM(a_, accv) do {                                             \
    _Pragma("unroll")                                                         \
    for (int pc = 0; pc < 4; ++pc) {                                          \
        half4_t hv;                                                           \
        _Pragma("unroll")                                                     \
        for (int j = 0; j < 4; ++j) hv[j] = (half_t)accv[pc][j];              \
        int byte_ = ((a_) * 2048 + pc * 512 + g * 128 + c * 8) ^              \
                    (((a_) & 7) << 4);                                        \
        *reinterpret_cast<half4_t*>(reinterpret_cast<char*>(xba2s) + byte_) = hv; \
    }                                                                         \
} while (0)

#define WAIT_VM(n) do {                                                       \
    asm volatile("s_waitcnt vmcnt(" #n ")" ::: "memory");                     \
    __builtin_amdgcn_sched_barrier(0);                                        \
} while (0)

#define WAIT_LGKM() do {                                                      \
    asm volatile("s_waitcnt lgkmcnt(0)" ::: "memory");                        \
    __builtin_amdgcn_sched_barrier(0);                                        \
} while (0)

#define SBAR() __builtin_amdgcn_sched_barrier(0)

// ---------------------------------------------------------------------------
// Fused steps 3-5, MFMA f16. 32 atoms / block, 8 waves, 512 threads.
//  phase 1: wave w -> atoms {4w..4w+3}; depth-4 gather pipeline, stage
//           regions = the atoms' own xba2s output regions (writes deferred).
//  phase 2: wave w -> (mt = w>>2, ot = w&3), FULL K=1024 (no split-K, no
//           preds, one fewer barrier); Wb2 8-deep register rotation.
//  phase 3: wave w -> oc [w*32,+32) for both mt halves.
//  LDS 68 KB -> 2 blocks/CU. Wb2/Wu2/out line-touches per atom halved.
// ---------------------------------------------------------------------------
__global__ __launch_bounds__(512, 4) void fused(const half_t* __restrict__ xbh,
                                                const float*  __restrict__ rad,   // (N,16,32) f32
                                                const int*    __restrict__ sidxg, // (N,32)
                                                const half_t* __restrict__ Wb2,   // (65536) permuted
                                                const half_t* __restrict__ Wu2,   // (16384) permuted
                                                const half_t* __restrict__ zrow,  // 128 zero f16
                                                float* __restrict__ out) {        // (N,256)
    __shared__ __align__(16) half_t xba2s[32 * 1024];  // 64 KB, outputs + stage (aliased)
    __shared__ __align__(16) half_t houts[32 * 64];    //  4 KB, row-swizzled

    const int t = threadIdx.x;
    const int w = t >> 6;        // wave 0..7
    const int l = t & 63;
    const int c = l & 15;
    const int g = l >> 4;
    const int a0 = blockIdx.x * NATILE;

    char* Rb = reinterpret_cast<char*>(xba2s) + w * 8192;  // wave's 4 atom regions

    const f32x4 fzero = {0.f, 0.f, 0.f, 0.f};

    // ---- FIFO prologue (order pinned by sched_barriers; vmcnt counts rely on it)
    // ops 1-2: sidx for 4 atoms (2 loads; clamped for the tail block)
    int ga_s0 = a0 + w * 4 + (l >> 5);     if (ga_s0 > N_ATOMS - 1) ga_s0 = N_ATOMS - 1;
    int ga_s1 = a0 + w * 4 + 2 + (l >> 5); if (ga_s1 > N_ATOMS - 1) ga_s1 = N_ATOMS - 1;
    int sv0 = sidxg[(size_t)ga_s0 * KMAX + (l & 31)];
    int sv1 = sidxg[(size_t)ga_s1 * KMAX + (l & 31)];
    // ops 3-10: rad, linear 1 KB loads (2 per atom)
    f32x4 rv[8];
    #pragma unroll
    for (int q = 0; q < 8; ++q) {
        int ga = a0 + w * 4 + (q >> 1); if (ga > N_ATOMS - 1) ga = N_ATOMS - 1;
        rv[q] = *reinterpret_cast<const f32x4*>(rad + (size_t)ga * 512 + (q & 1) * 256 + l * 4);
    }
    SBAR();
    // ops 11-18: gathers G0..G3 = kc0 of atoms 0..3 -> regions R0..R3
    ISSUE2(0, 0, sv0);
    ISSUE2(1, 0, sv0);
    ISSUE2(2, 0, sv1);
    ISSUE2(3, 0, sv1);
    SBAR();
    // ops 19-22: Wb2 prefetch j=0..3 (L2-resident)
    const int mt = w >> 2, ot = w & 3;
    const half_t* wbbase = &Wb2[(size_t)ot * 16384];
    half8_t bfr[8];
    #pragma unroll
    for (int j = 0; j < 4; ++j)
        bfr[j] = *reinterpret_cast<const half8_t*>(wbbase + j * 512 + l * 8);
    SBAR();

    // radF via shfl-both-then-select (dest-lane predicate AFTER the shfl):
    //   radF[as][kc][j] = rad[atom as][r=c][k=kc*16+g*4+j]
    // (compiler inserts vmcnt(12) here for rv -> gathers+Wb2 stay in flight)
    half4_t radF[4][2];
    #pragma unroll
    for (int as = 0; as < 4; ++as)
        #pragma unroll
        for (int kc = 0; kc < 2; ++kc) {
            int srcl = (c & 7) * 8 + kc * 4 + g;
            #pragma unroll
            for (int j = 0; j < 4; ++j) {
                float lo = __shfl(rv[as * 2 + 0][j], srcl, 64);
                float hi = __shfl(rv[as * 2 + 1][j], srcl, 64);
                radF[as][kc][j] = (half_t)((c & 8) ? hi : lo);
            }
        }

    half4_t ident;  // identity B-frag: B[k][n] = (k==n)
    #pragma unroll
    for (int j = 0; j < 4; ++j) ident[j] = (half_t)((g * 4 + j == c) ? 1.0f : 0.0f);

    f32x4 accA[4] = {fzero, fzero, fzero, fzero};
    f32x4 accB[4] = {fzero, fzero, fzero, fzero};
    f32x4 accC[4] = {fzero, fzero, fzero, fzero};
    f32x4 accD[4] = {fzero, fzero, fzero, fzero};

    // ---- depth-4 consume chain; outstanding at start = G0..G3(8) + Wb2(4) = 12
    WAIT_VM(10);  consume_batch(Rb,        c, g, radF[0][0], ident, accA);
    WAIT_LGKM();  ISSUE2(0, 1, sv0);   // G4 -> R0
    WAIT_VM(10);  consume_batch(Rb + 2048, c, g, radF[1][0], ident, accB);
    WAIT_LGKM();  ISSUE2(1, 1, sv0);   // G5 -> R1
    WAIT_VM(10);  consume_batch(Rb + 4096, c, g, radF[2][0], ident, accC);
    WAIT_LGKM();  ISSUE2(2, 1, sv1);   // G6 -> R2
    WAIT_VM(10);  consume_batch(Rb + 6144, c, g, radF[3][0], ident, accD);
    WAIT_LGKM();  ISSUE2(3, 1, sv1);   // G7 -> R3
    WAIT_VM(6);   consume_batch(Rb,        c, g, radF[0][1], ident, accA); // drains Wb2+G4
    WAIT_VM(4);   consume_batch(Rb + 2048, c, g, radF[1][1], ident, accB);
    WAIT_VM(2);   consume_batch(Rb + 4096, c, g, radF[2][1], ident, accC);
    WAIT_VM(0);   consume_batch(Rb + 6144, c, g, radF[3][1], ident, accD);
    WAIT_LGKM();
    WRITE_ATOM(w * 4 + 0, accA);
    WRITE_ATOM(w * 4 + 1, accB);
    WRITE_ATOM(w * 4 + 2, accC);
    WRITE_ATOM(w * 4 + 3, accD);

    // issue Wb2 j=4..7 (fly during the barrier)
    #pragma unroll
    for (int j = 4; j < 8; ++j)
        bfr[j] = *reinterpret_cast<const half8_t*>(wbbase + j * 512 + l * 8);

    __syncthreads();

    // ---------------- phase 2: h_out(32x64) = xba2(32x1024) @ Wb ------------
    // wave (mt, ot): rows mt*16.., o = ot*16+c; K=1024 = 32 steps, 8-deep bfr.
    {
        f32x4 acc2[4] = {fzero, fzero, fzero, fzero};
        #pragma unroll
        for (int j = 0; j < 32; ++j) {
            int abyte = ((mt * 16 + c) * 2048 + j * 64 + g * 16) ^ ((c & 7) << 4);
            half8_t af = *reinterpret_cast<const half8_t*>(
                reinterpret_cast<const char*>(xba2s) + abyte);
            acc2[j & 3] = __builtin_amdgcn_mfma_f32_16x16x32_f16(af, bfr[j & 7], acc2[j & 3], 0, 0, 0);
            if (j < 24)
                bfr[j & 7] = *reinterpret_cast<const half8_t*>(wbbase + (j + 8) * 512 + l * 8);
        }
        f32x4 accT = acc2[0] + acc2[1] + acc2[2] + acc2[3];
        // houts[m = mt*16 + g*4+i][o = ot*16+c], row-swizzled, f16
        #pragma unroll
        for (int i = 0; i < 4; ++i) {
            int m = mt * 16 + g * 4 + i;
            int byte_ = (m * 128 + (ot * 16 + c) * 2) ^ ((m & 7) << 4);
            *reinterpret_cast<half_t*>(reinterpret_cast<char*>(houts) + byte_) = (half_t)accT[i];
        }
    }

    // prefetch all 4 Wu2 fragments across the barrier
    half8_t wuf[2][2];
    #pragma unroll
    for (int nt = 0; nt < 2; ++nt)
        #pragma unroll
        for (int kk = 0; kk < 2; ++kk)
            wuf[nt][kk] = *reinterpret_cast<const half8_t*>(
                &Wu2[(size_t)(((w * 2 + nt) * 2 + kk) * 64 + l) * 8]);

    __syncthreads();

    // ---------------- phase 3: out(32x256) = hout(32x64) @ Wu ---------------
    #pragma unroll
    for (int mt2 = 0; mt2 < 2; ++mt2) {
        half8_t ha[2];
        #pragma unroll
        for (int kk = 0; kk < 2; ++kk) {
            int byte_ = ((mt2 * 16 + c) * 128 + kk * 64 + g * 16) ^ ((c & 7) << 4);
            ha[kk] = *reinterpret_cast<const half8_t*>(
                reinterpret_cast<const char*>(houts) + byte_);
        }
        #pragma unroll
        for (int nt = 0; nt < 2; ++nt) {
            f32x4 acc3 = fzero;
            acc3 = __builtin_amdgcn_mfma_f32_16x16x32_f16(ha[0], wuf[nt][0], acc3, 0, 0, 0);
            acc3 = __builtin_amdgcn_mfma_f32_16x16x32_f16(ha[1], wuf[nt][1], acc3, 0, 0, 0);
            #pragma unroll
            for (int i = 0; i < 4; ++i) {
                int row = a0 + mt2 * 16 + g * 4 + i;
                if (row < N_ATOMS)
                    out[(size_t)row * 256 + w * 32 + nt * 16 + c] = acc3[i];
            }
        }
    }
}

// ---------------------------------------------------------------------------
extern "C" void kernel_launch(void* const* d_in, const int* in_sizes, int n_in,
                              void* d_out, int out_size, void* d_ws, size_t ws_size,
                              hipStream_t stream) {
    const float* h   = (const float*)d_in[0];
    const float* rad = (const float*)d_in[1];
    const int*   ei  = (const int*)d_in[2];
    const int*   tni = (const int*)d_in[3];
    const float* Wd  = (const float*)d_in[4];
    const float* Wb  = (const float*)d_in[5];
    const float* Wu  = (const float*)d_in[6];
    float* out = (float*)d_out;

    // workspace: xbh f16 6.4MB | sidx i32 6.4MB | Wb2 128KB | Wu2 32KB | zrow 256B
    half_t* xbh  = (half_t*)d_ws;
    int*    sidx = (int*)((char*)d_ws + (size_t)N_ATOMS * EP_IN * sizeof(half_t));
    half_t* Wb2  = (half_t*)((char*)sidx + (size_t)NEDGES * sizeof(int));
    half_t* Wu2  = Wb2 + 64 * 1024;
    half_t* zrow = Wu2 + 16384;

    prep_all<<<PREP_NB, 256, 0, stream>>>(h, Wd, ei, tni, Wb, Wu,
                                          xbh, sidx, Wb2, Wu2, zrow);
    fused<<<FUSED_NB, 512, 0, stream>>>(xbh, rad, sidx, Wb2, Wu2, zrow, out);
}